// Round 8
// baseline (291.312 us; speedup 1.0000x reference)
//
#include <hip/hip_runtime.h>
#include <hip/hip_bf16.h>

#define BATCH 8
#define NSEQ 1024
#define DIMM 448
#define NHEAD 7
#define HDIM 64
#define MROWS (BATCH*NSEQ)   // 8192
#define KDIM 448
// scale * log2(e): fold softmax scale + exp->exp2 conversion into Q prescale
#define CB 0.18033688f

typedef short short8 __attribute__((ext_vector_type(8)));
typedef int   int4v  __attribute__((ext_vector_type(4)));
typedef float floatx16 __attribute__((ext_vector_type(16)));
typedef unsigned int u32;

#define MFMA32(a,b,c) __builtin_amdgcn_mfma_f32_32x32x16_bf16(a,b,c,0,0,0)

__device__ __forceinline__ unsigned short f2bf(float f){
    __hip_bfloat16 h = __float2bfloat16(f);
    return *reinterpret_cast<unsigned short*>(&h);
}
__device__ __forceinline__ float bf2f(unsigned short u){
    __hip_bfloat16 h; *reinterpret_cast<unsigned short*>(&h) = u;
    return __bfloat162float(h);
}
__device__ __forceinline__ short8 i4_to_s8(int4v v){
    union { int4v i; short8 s; } u; u.i = v; return u.s;
}

// ---------------------------------------------------------------------------
// prep: ek -> bf16; wqv -> [896][448] bf16 T; wout -> [512][448] split T (pad)
//   [0,448)    ek cvt (1 float4/thread)
//   [448,644)  wqvT (4x 64-lane units/block)
//   [644,756)  woT split + zero-pad rows 448..511
// ---------------------------------------------------------------------------
__global__ __launch_bounds__(256)
void prep_r8(const float* __restrict__ ek, const float* __restrict__ wqv,
             const float* __restrict__ wout,
             unsigned short* __restrict__ ekh, unsigned short* __restrict__ wqvTh,
             unsigned short* __restrict__ woTh, unsigned short* __restrict__ woTl)
{
    const int bx = blockIdx.x, tid = threadIdx.x;
    if (bx < 448) {
        int i = bx*256 + tid;
        float4 v = ((const float4*)ek)[i];
        ((ushort4*)ekh)[i] = make_ushort4(f2bf(v.x), f2bf(v.y), f2bf(v.z), f2bf(v.w));
    } else if (bx < 644) {
        int lid = (bx-448)*4 + (tid>>6);     // 0..783 = kc(56) x ng(14)
        int kc = lid % 56, ng = lid / 56;
        int n = ng*64 + (tid&63);
        unsigned short h[8];
#pragma unroll
        for (int j = 0; j < 8; ++j) h[j] = f2bf(wqv[(size_t)(kc*8+j)*896 + n]);
        size_t o = (size_t)n*KDIM + kc*8;
        *(ushort4*)(wqvTh + o)     = make_ushort4(h[0],h[1],h[2],h[3]);
        *(ushort4*)(wqvTh + o + 4) = make_ushort4(h[4],h[5],h[6],h[7]);
    } else {
        int lid = (bx-644)*4 + (tid>>6);     // 0..447 = kc(56) x ng(8)
        int kc = lid % 56, ng = lid / 56;
        int n = ng*64 + (tid&63);
        ushort4 h0={0,0,0,0}, h1={0,0,0,0}, l0={0,0,0,0}, l1={0,0,0,0};
        if (n < DIMM) {
            unsigned short h[8], l[8];
#pragma unroll
            for (int j = 0; j < 8; ++j) {
                float f = wout[(size_t)(kc*8+j)*DIMM + n];
                h[j] = f2bf(f); l[j] = f2bf(f - bf2f(h[j]));
            }
            h0 = make_ushort4(h[0],h[1],h[2],h[3]); h1 = make_ushort4(h[4],h[5],h[6],h[7]);
            l0 = make_ushort4(l[0],l[1],l[2],l[3]); l1 = make_ushort4(l[4],l[5],l[6],l[7]);
        }
        size_t o = (size_t)n*KDIM + kc*8;
        *(ushort4*)(woTh + o) = h0; *(ushort4*)(woTh + o + 4) = h1;
        *(ushort4*)(woTl + o) = l0; *(ushort4*)(woTl + o + 4) = l1;
    }
}

// ---------------------------------------------------------------------------
// gemm1: qv = x @ w_qv. A read fp32 DIRECTLY (cvt at use), B single bf16.
// Block = 4 waves stacked on m (same n-range -> B shared via L1).
// Wave tile 32m x 128n, depth-2 reg prefetch, no LDS/barriers.
// q output PRESCALED by CB. grid (64, 7), block 256.
// ---------------------------------------------------------------------------
__global__ __launch_bounds__(256, 2)
void gemm1_r8(const float* __restrict__ x, const unsigned short* __restrict__ Bh,
              unsigned short* __restrict__ qd, unsigned short* __restrict__ vTd)
{
    const int tid = threadIdx.x, w = tid >> 6, lane = tid & 63;
    const int lq = lane & 31, lh = lane >> 5;
    const int m0 = blockIdx.x*128 + w*32, n0 = blockIdx.y*128;
    const float* aB = x + (size_t)(m0 + lq)*KDIM + lh*8;
    const unsigned short* bB = Bh + (size_t)(n0 + lq)*KDIM + lh*8;

    floatx16 acc[4] = {};
    float4 aF[2][2][2];            // [slot][c][half]
    short8 bR[2][8];
#define LD1(kt, sl) {                                                          \
    _Pragma("unroll") for (int c = 0; c < 2; ++c) {                            \
        aF[sl][c][0] = *(const float4*)(aB + (kt)*32 + c*16);                  \
        aF[sl][c][1] = *(const float4*)(aB + (kt)*32 + c*16 + 4);              \
        _Pragma("unroll") for (int fn = 0; fn < 4; ++fn)                       \
            bR[sl][fn*2+c] = *(const short8*)(bB + (size_t)(fn*32)*KDIM + (kt)*32 + c*16); } }

    LD1(0, 0)
#pragma unroll
    for (int kt = 0; kt < 14; ++kt) {
        if (kt < 13) LD1(kt+1, (kt+1)&1)
        const int sl = kt & 1;
#pragma unroll
        for (int c = 0; c < 2; ++c) {
            float4 f0 = aF[sl][c][0], f1 = aF[sl][c][1];
            short8 a;
            a[0]=(short)f2bf(f0.x); a[1]=(short)f2bf(f0.y);
            a[2]=(short)f2bf(f0.z); a[3]=(short)f2bf(f0.w);
            a[4]=(short)f2bf(f1.x); a[5]=(short)f2bf(f1.y);
            a[6]=(short)f2bf(f1.z); a[7]=(short)f2bf(f1.w);
#pragma unroll
            for (int fn = 0; fn < 4; ++fn)
                acc[fn] = MFMA32(a, bR[sl][fn*2+c], acc[fn]);
        }
    }
#undef LD1

#pragma unroll
    for (int fn = 0; fn < 4; ++fn) {
        const int gn = n0 + fn*32 + lq;
        const int hcol = gn >> 6, d = gn & 63;
#pragma unroll
        for (int r = 0; r < 16; ++r) {
            const int gm = m0 + (r&3) + 8*(r>>2) + 4*lh;
            const int b = gm >> 10, ns = gm & 1023;
            if (hcol < NHEAD)   // q: prescale by CB (softmax scale * log2e)
                qd[((size_t)((b*NHEAD + hcol)*NSEQ + ns))*HDIM + d] = f2bf(acc[fn][r]*CB);
            else                // v: transposed [b][h][d][n]
                vTd[((size_t)((b*NHEAD + hcol - NHEAD)*HDIM + d))*NSEQ + ns] = f2bf(acc[fn][r]);
        }
    }
}

// ---------------------------------------------------------------------------
// attn6: barrier-free flash attention, batch-sharing blocks.
// Block = 512 thr = 8 waves = 8 BATCHES, all at the same (head, qt32):
// K-tile and bias addresses are IDENTICAL across the 8 waves -> L1-shared.
// V (private per wave) uses nontemporal loads to keep it out of L1.
// Bias read directly from eb (fp32) in D-fragment order; no prep pass.
// Q prescaled by CB -> p = exp2(fma(bias, CB, S)). No-max softmax (bounded).
// P transposed D->A frag via shfl_xor(32). l via VALU + tiny LDS transpose.
// grid (32 qt, 7 h), depth-2 register prefetch, zero __syncthreads.
// ---------------------------------------------------------------------------
__global__ __launch_bounds__(512, 2)
void attn6(const unsigned short* __restrict__ qh_g, const unsigned short* __restrict__ vTh,
           const unsigned short* __restrict__ ekh, const float* __restrict__ eb,
           unsigned short* __restrict__ aoh, unsigned short* __restrict__ aol)
{
    __shared__ float linv[8][32];

    const int tid = threadIdx.x;
    const int w = tid >> 6;            // wave = batch
    const int lane = tid & 63;
    const int lq = lane & 31, lh = lane >> 5;
    const int qt = blockIdx.x, h = blockIdx.y;
    const int bh = w*NHEAD + h;

    short8 qf[4];
#pragma unroll
    for (int c = 0; c < 4; ++c)
        qf[c] = *(const short8*)(qh_g +
            ((size_t)(bh*NSEQ) + qt*32 + lq)*HDIM + c*16 + lh*8);

    const unsigned short* kB = ekh + ((size_t)h*NSEQ + lq)*HDIM + lh*8;
    const unsigned short* vB = vTh + ((size_t)(bh*HDIM) + lq)*NSEQ;
    const float* bB = eb + ((size_t)(h*NSEQ) + qt*32 + lq)*NSEQ;

    short8 kR[2][4], vR[2][4];
    float4 bR[2][4];
#define PREF(MM, SL) {                                                         \
    _Pragma("unroll") for (int c = 0; c < 4; ++c)                              \
        kR[SL][c] = *(const short8*)(kB + (size_t)(MM)*2048 + c*16);           \
    _Pragma("unroll") for (int fn = 0; fn < 2; ++fn)                           \
    _Pragma("unroll") for (int c2 = 0; c2 < 2; ++c2)                           \
        vR[SL][fn*2+c2] = __builtin_nontemporal_load(                          \
            (const short8*)(vB + (size_t)(fn*32)*NSEQ + (MM)*32 + c2*16 + lh*8)); \
    _Pragma("unroll") for (int g = 0; g < 4; ++g)                              \
        bR[SL][g] = *(const float4*)(bB + (size_t)(MM)*32 + g*8 + lh*4); }

    floatx16 O[2] = {};
    float ls = 0.f;

#define SEC(J, PAR, NXT) {                                                     \
    { const int mm_ = ((J)+1 < 32) ? (J)+1 : 0; PREF(mm_, NXT) }               \
    floatx16 S = {};                                                           \
    S = MFMA32(kR[PAR][0], qf[0], S);                                          \
    S = MFMA32(kR[PAR][1], qf[1], S);                                          \
    S = MFMA32(kR[PAR][2], qf[2], S);                                          \
    S = MFMA32(kR[PAR][3], qf[3], S);                                          \
    u32 Pq[4][2];                                                              \
    _Pragma("unroll") for (int g = 0; g < 4; ++g) {                            \
        float bvv[4] = {bR[PAR][g].x, bR[PAR][g].y, bR[PAR][g].z, bR[PAR][g].w}; \
        unsigned short hb[4];                                                  \
        _Pragma("unroll") for (int j = 0; j < 4; ++j) {                        \
            float pv = __builtin_amdgcn_exp2f(fmaf(bvv[j], CB, S[g*4+j]));     \
            ls += pv;  hb[j] = f2bf(pv);                                       \
        }                                                                      \
        Pq[g][0] = (u32)hb[0] | ((u32)hb[1] << 16);                            \
        Pq[g][1] = (u32)hb[2] | ((u32)hb[3] << 16);                            \
    }                                                                          \
    u32 pp[4][2];                                                              \
    _Pragma("unroll") for (int g = 0; g < 4; ++g) {                            \
        pp[g][0] = (u32)__shfl_xor((int)Pq[g][0], 32);                         \
        pp[g][1] = (u32)__shfl_xor((int)Pq[g][1], 32);                         \
    }                                                                          \
    _Pragma("unroll") for (int c2 = 0; c2 < 2; ++c2) {                         \
        int4v iv;                                                              \
        iv.x = lh ? (int)pp[2*c2+1][0] : (int)Pq[2*c2][0];                     \
        iv.y = lh ? (int)pp[2*c2+1][1] : (int)Pq[2*c2][1];                     \
        iv.z = lh ? (int)Pq[2*c2+1][0] : (int)pp[2*c2][0];                     \
        iv.w = lh ? (int)Pq[2*c2+1][1] : (int)pp[2*c2][1];                     \
        short8 af = i4_to_s8(iv);                                              \
        O[0] = MFMA32(af, vR[PAR][0*2+c2], O[0]);                              \
        O[1] = MFMA32(af, vR[PAR][1*2+c2], O[1]);                              \
    } }

    PREF(0, 0)
#pragma unroll
    for (int jj = 0; jj < 16; ++jj) {
        SEC(2*jj,   0, 1)
        SEC(2*jj+1, 1, 0)
    }
#undef SEC
#undef PREF

    // l lives per-column (q = lq); O rows need it per-row -> tiny per-wave
    // LDS transpose (intra-wave: program order + lgkmcnt, no barrier).
    float lt = ls + __shfl_xor(ls, 32);
    if (lh == 0) linv[w][lq] = 1.0f / lt;

    const size_t obase = ((size_t)(w*NSEQ) + qt*32)*DIMM + h*HDIM;
#pragma unroll
    for (int r = 0; r < 16; ++r) {
        const int qr = (r&3) + 8*(r>>2) + 4*lh;
        const float inv = linv[w][qr];
        float v0 = O[0][r]*inv, v1 = O[1][r]*inv;
        unsigned short h0 = f2bf(v0), h1 = f2bf(v1);
        size_t o = obase + (size_t)qr*DIMM + lq;
        aoh[o]      = h0;  aol[o]      = f2bf(v0 - bf2f(h0));
        aoh[o + 32] = h1;  aol[o + 32] = f2bf(v1 - bf2f(h1));
    }
}

// ---------------------------------------------------------------------------
// gemm2: out = ao @ w_out + b_out, 3-term split-2. Block = 4 waves on m,
// shared 128-wide n (B via L1). Wave 32m x 128n, depth-2, no LDS/barriers.
// grid (64, 4) over padded N=512; stores masked to gn<448. block 256.
// ---------------------------------------------------------------------------
__global__ __launch_bounds__(256, 1)
void gemm2_r8(const unsigned short* __restrict__ Ah, const unsigned short* __restrict__ Al,
              const unsigned short* __restrict__ Bh, const unsigned short* __restrict__ Bl,
              const float* __restrict__ bias, float* __restrict__ out)
{
    const int tid = threadIdx.x, w = tid >> 6, lane = tid & 63;
    const int lq = lane & 31, lh = lane >> 5;
    const int m0 = blockIdx.x*128 + w*32, n0 = blockIdx.y*128;
    const unsigned short* aHB = Ah + (size_t)(m0 + lq)*KDIM + lh*8;
    const unsigned short* aLB = Al + (size_t)(m0 + lq)*KDIM + lh*8;
    const unsigned short* bHB = Bh + (size_t)(n0 + lq)*KDIM + lh*8;
    const unsigned short* bLB = Bl + (size_t)(n0 + lq)*KDIM + lh*8;

    floatx16 acc[4] = {};
    short8 aH[2][2], aL[2][2], bH[2][8], bL[2][8];
#define LD2(kt, sl) {                                                          \
    _Pragma("unroll") for (int c = 0; c < 2; ++c) {                            \
        aH[sl][c] = *(const short8*)(aHB + (kt)*32 + c*16);                    \
        aL[sl][c] = *(const short8*)(aLB + (kt)*32 + c*16);                    \
        _Pragma("unroll") for (int fn = 0; fn < 4; ++fn) {                     \
            bH[sl][fn*2+c] = *(const short8*)(bHB + (size_t)(fn*32)*KDIM + (kt)*32 + c*16); \
            bL[sl][fn*2+c] = *(const short8*)(bLB + (size_t)(fn*32)*KDIM + (kt)*32 + c*16); } } }

    LD2(0, 0)
#pragma unroll
    for (int kt = 0; kt < 14; ++kt) {
        if (kt < 13) LD2(kt+1, (kt+1)&1)
        const int sl = kt & 1;
#pragma unroll
        for (int c = 0; c < 2; ++c)
#pragma unroll
            for (int fn = 0; fn < 4; ++fn) {
                acc[fn] = MFMA32(aH[sl][c], bH[sl][fn*2+c], acc[fn]);
                acc[fn] = MFMA32(aL[sl][c], bH[sl][fn*2+c], acc[fn]);
                acc[fn] = MFMA32(aH[sl][c], bL[sl][fn*2+c], acc[fn]);
            }
    }
#undef LD2

#pragma unroll
    for (int fn = 0; fn < 4; ++fn) {
        const int gn = n0 + fn*32 + lq;
        if (gn < DIMM) {
            const float bv = bias[gn];
#pragma unroll
            for (int r = 0; r < 16; ++r) {
                const int gm = m0 + (r&3) + 8*(r>>2) + 4*lh;
                out[(size_t)gm*DIMM + gn] = acc[fn][r] + bv;
            }
        }
    }
}

// ---------------------------------------------------------------------------
extern "C" void kernel_launch(void* const* d_in, const int* in_sizes, int n_in,
                              void* d_out, int out_size, void* d_ws, size_t ws_size,
                              hipStream_t stream)
{
    const float* x    = (const float*)d_in[0];
    const float* wqv  = (const float*)d_in[1];
    const float* ek   = (const float*)d_in[2];
    const float* eb   = (const float*)d_in[3];
    const float* wout = (const float*)d_in[4];
    const float* bout = (const float*)d_in[5];
    float* out = (float*)d_out;

    const size_t MK = (size_t)MROWS*KDIM;        // 3,670,016
    const size_t EK = (size_t)NHEAD*NSEQ*HDIM;   // 458,752
    unsigned short* p = (unsigned short*)d_ws;
    unsigned short* ekh   = p;  p += EK;
    unsigned short* wqvTh = p;  p += (size_t)896*KDIM;
    unsigned short* woTh  = p;  p += (size_t)512*KDIM;
    unsigned short* woTl  = p;  p += (size_t)512*KDIM;
    unsigned short* qh    = p;  p += MK;
    unsigned short* vTh   = p;  p += MK;
    unsigned short* aoh   = p;  p += MK;
    unsigned short* aol   = p;  p += MK;

    prep_r8<<<756, 256, 0, stream>>>(ek, wqv, wout, ekh, wqvTh, woTh, woTl);
    gemm1_r8<<<dim3(64, 7), 256, 0, stream>>>(x, wqvTh, qh, vTh);
    attn6<<<dim3(32, NHEAD), 512, 0, stream>>>(qh, vTh, ekh, eb, aoh, aol);
    gemm2_r8<<<dim3(64, 4), 256, 0, stream>>>(aoh, aol, woTh, woTl, bout, out);
}